// Round 18
// baseline (151.804 us; speedup 1.0000x reference)
//
#include <hip/hip_runtime.h>

// LRU r18: r17-green pipeline; ONLY k3b changed -> v4: M=32/block, 256 thr
// (4 waves x 64 cols, 4 B-frags/kk), breg dbuf 12x2, 3 blocks/CU.
// Rationale: af-LDS-read redundancy = 256/cols_per_wave; 64 cols cuts the
// device LDS-read time 31us -> 8us and 49.6KB LDS gives 3 resident blocks.
// k3a/k3b split PERMANENT (r3/r4, r9/r10, r14/r15 all failed intra-kernel
// state->MFMA feeds; split is green).
// d_out = [0,64MB) output f32 | [64,128MB) inner-real f32.
// Region lifecycle:
//   [0,64MB):  k1 writes packed Bu (bf16 re|im u32) -> k3a reads then
//              overwrites per-thread with packed bf16 states -> k3b stages its
//              32 rows (before barrier) then epilogue overwrites with output.
//   [64,128MB): untouched until k3a writes inner-real f32 (exact, final).

typedef float  f32x4 __attribute__((ext_vector_type(4)));
typedef short  s16x8 __attribute__((ext_vector_type(8)));

__device__ __forceinline__ unsigned short f2bf(float x) {
  unsigned int u = __builtin_bit_cast(unsigned int, x);
  u += 0x7FFFu + ((u >> 16) & 1u);            // round-to-nearest-even
  return (unsigned short)(u >> 16);
}
__device__ __forceinline__ float bf2f(unsigned int s) {
  unsigned int u = s << 16;
  return __builtin_bit_cast(float, u);
}
__device__ __forceinline__ f32x4 mfma16(s16x8 a, s16x8 b, f32x4 c) {
  return __builtin_amdgcn_mfma_f32_16x16x32_bf16(a, b, c, 0, 0, 0);
}

// ---------------------------------------------------------------------------
// K0: W1 bf16 tiled + W2f f32 [k*256+o] + lam arrays (green, unchanged).
// ---------------------------------------------------------------------------
__global__ void k0_mix(const float* __restrict__ nu_log, const float* __restrict__ theta_log,
                       const float* __restrict__ gamma_log,
                       const float* __restrict__ B_re, const float* __restrict__ B_im,
                       const float* __restrict__ C_re, const float* __restrict__ C_im,
                       const float* __restrict__ Dm,
                       unsigned short* __restrict__ W1, float* __restrict__ W2f,
                       float* __restrict__ lamre, float* __restrict__ lamim,
                       float* __restrict__ lamLre, float* __restrict__ lamLim) {
  int idx = blockIdx.x * 256 + threadIdx.x;
  if (idx < 131072) {
    int ki = idx & 31; int np_ = (idx >> 5) & 511; int kk = idx >> 14;
    int k = kk * 32 + ki; int n = np_ & 255;
    float g = expf(gamma_log[n]);
    float v = (np_ < 256) ? B_re[n * 256 + k] : B_im[n * 256 + k];
    W1[idx] = f2bf(g * v);
  } else if (idx < 327680) {
    int j = idx - 131072;
    int k = j >> 8, o = j & 255;
    float v;
    if (k < 512) { int n = k >> 1; v = (k & 1) ? -C_im[o * 256 + n] : C_re[o * 256 + n]; }
    else         { v = Dm[o * 256 + (k - 512)]; }
    W2f[j] = v;
  } else if (idx < 327936) {
    int n = idx - 327680;
    float la = expf(-expf(nu_log[n]));
    float th = expf(theta_log[n]);
    float lr = la * cosf(th), li = la * sinf(th);
    lamre[n] = lr; lamim[n] = li;
    float r = lr, i = li;
    #pragma unroll
    for (int t = 0; t < 5; ++t) { float nr = r * r - i * i; float ni = 2.f * r * i; r = nr; i = ni; }
    lamLre[n] = r; lamLim[n] = i;
  }
}

// ---------------------------------------------------------------------------
// K0b: tile W2f into bf16 W2t[(kk*256+o)*32+ki] (green, unchanged).
// ---------------------------------------------------------------------------
__global__ void k0b_tile(const float* __restrict__ W2f, unsigned short* __restrict__ W2t) {
  int j = blockIdx.x * 256 + threadIdx.x;          // [0,196608)
  int ki = j & 31, o = (j >> 5) & 255, kk = j >> 13;
  W2t[j] = f2bf(W2f[(kk * 32 + ki) * 256 + o]);
}

// ---------------------------------------------------------------------------
// K1 v2 (green r17, unchanged): B-register-stationary Bu-GEMM + packed stores
// + in-register chunk reduction.
// ---------------------------------------------------------------------------
__global__ __launch_bounds__(1024, 4) void k1_bstat(const float* __restrict__ in,
                                                    const unsigned short* __restrict__ W1,
                                                    unsigned int* __restrict__ BuP,
                                                    const float* __restrict__ lamre,
                                                    const float* __restrict__ lamim,
                                                    float2* __restrict__ cl) {
  __shared__ unsigned short lA[64 * 264];   // 33792 B
  int tid = threadIdx.x, lane = tid & 63, w = tid >> 6;   // w in [0,16)
  int l15 = lane & 15, q = lane >> 4;
  int n = w * 16 + l15;
  size_t row0 = (size_t)blockIdx.x * 64;

  s16x8 breg[2][2][2];                      // [buf][plane][t]
  auto loadB = [&](int buf, int ph) {
    #pragma unroll
    for (int p = 0; p < 2; ++p)
      #pragma unroll
      for (int t = 0; t < 2; ++t) {
        int kk = ph * 2 + t;
        breg[buf][p][t] = *reinterpret_cast<const s16x8*>(
            W1 + (size_t)(kk * 512 + p * 256 + n) * 32 + q * 8);
      }
  };

  loadB(0, 0);                              // issue early, overlaps staging

  #pragma unroll
  for (int i = 0; i < 4; ++i) {
    int chunk = i * 1024 + tid;             // 4096 float4 chunks
    int m = chunk >> 6, h0 = (chunk & 63) * 4;
    float4 v = *reinterpret_cast<const float4*>(in + (row0 + m) * 256 + h0);
    ushort4 s; s.x = f2bf(v.x); s.y = f2bf(v.y); s.z = f2bf(v.z); s.w = f2bf(v.w);
    *reinterpret_cast<ushort4*>(&lA[m * 264 + h0]) = s;
  }
  __syncthreads();

  f32x4 acc[4][2];
  #pragma unroll
  for (int mt = 0; mt < 4; ++mt)
    #pragma unroll
    for (int p = 0; p < 2; ++p) acc[mt][p] = f32x4{0.f, 0.f, 0.f, 0.f};

  #pragma unroll
  for (int ph = 0; ph < 4; ++ph) {
    const int cur = ph & 1;
    if (ph < 3) loadB(cur ^ 1, ph + 1);     // prefetch next phase into other buf
    #pragma unroll
    for (int t = 0; t < 2; ++t) {
      int kk = ph * 2 + t;
      #pragma unroll
      for (int mt = 0; mt < 4; ++mt) {
        s16x8 af = *reinterpret_cast<const s16x8*>(
            &lA[(mt * 16 + l15) * 264 + kk * 32 + q * 8]);
        acc[mt][0] = mfma16(af, breg[cur][0][t], acc[mt][0]);
        acc[mt][1] = mfma16(af, breg[cur][1][t], acc[mt][1]);
      }
    }
  }

  // epilogue: pack (re,im) bf16 pairs
  #pragma unroll
  for (int mt = 0; mt < 4; ++mt)
    #pragma unroll
    for (int r = 0; r < 4; ++r) {
      size_t row = row0 + mt * 16 + q * 4 + r;
      unsigned int pk = (unsigned int)f2bf(acc[mt][0][r]) |
                        ((unsigned int)f2bf(acc[mt][1][r]) << 16);
      BuP[row * 256 + n] = pk;
    }

  // in-register chunk reduction (r17-green algebra)
  {
    float lr = lamre[n], li = lamim[n];
    float l2r = lr * lr - li * li, l2i = 2.f * lr * li;
    float l4r = l2r * l2r - l2i * l2i, l4i = 2.f * l2r * l2i;
    float p8r = l4r * l4r - l4i * l4i, p8i = 2.f * l4r * l4i;
    float p12r = p8r * l4r - p8i * l4i, p12i = p8r * l4i + p8i * l4r;
    float p16r = p8r * p8r - p8i * p8i, p16i = 2.f * p8r * p8i;
    float e1r, e1i;                         // lam^{12-4q}
    if (q == 0)      { e1r = p12r; e1i = p12i; }
    else if (q == 1) { e1r = p8r;  e1i = p8i;  }
    else if (q == 2) { e1r = l4r;  e1i = l4i;  }
    else             { e1r = 1.f;  e1i = 0.f;  }
    float e0r = e1r * p16r - e1i * p16i;    // lam^{28-4q}
    float e0i = e1r * p16i + e1i * p16r;
    #pragma unroll
    for (int ch = 0; ch < 2; ++ch) {
      float hr[2], hi[2];
      #pragma unroll
      for (int h = 0; h < 2; ++h) {
        int mt = ch * 2 + h;
        float xr = 0.f, xi = 0.f;
        #pragma unroll
        for (int r = 0; r < 4; ++r) {
          float br = acc[mt][0][r], bi2 = acc[mt][1][r];
          float nr2 = lr * xr - li * xi + br;
          float ni2 = lr * xi + li * xr + bi2;
          xr = nr2; xi = ni2;
        }
        hr[h] = xr; hi[h] = xi;
      }
      float Tr = e0r * hr[0] - e0i * hi[0] + e1r * hr[1] - e1i * hi[1];
      float Ti = e0r * hi[0] + e0i * hr[0] + e1r * hi[1] + e1i * hr[1];
      Tr += __shfl_xor(Tr, 16); Ti += __shfl_xor(Ti, 16);
      Tr += __shfl_xor(Tr, 32); Ti += __shfl_xor(Ti, 32);
      if (q == 0) {
        size_t C = (size_t)blockIdx.x * 2 + ch;
        cl[C * 256 + n] = make_float2(Tr, Ti);
      }
    }
  }
}

// ---------------------------------------------------------------------------
// K2b: carry scan (green, unchanged).
// ---------------------------------------------------------------------------
__global__ void k2b_scan(const float2* __restrict__ cl, float2* __restrict__ cin,
                         const float* __restrict__ lamLre, const float* __restrict__ lamLim) {
  int b = blockIdx.x, n = threadIdx.x;
  float lr = lamLre[n], li = lamLim[n];
  float sr = 0.f, si = 0.f;
  #pragma unroll 4
  for (int c = 0; c < 128; ++c) {
    size_t idx = ((size_t)b * 128 + c) * 256 + n;
    float2 L = cl[idx];
    cin[idx] = make_float2(sr, si);
    float nr = lr * sr - li * si + L.x;
    float ni = lr * si + li * sr + L.y;
    sr = nr; si = ni;
  }
}

// ---------------------------------------------------------------------------
// K3a: f32 scan (green, unchanged). Reads packed Bu, overwrites with packed
// bf16 states (same thread/idx), writes inner-real f32 to second region.
// ---------------------------------------------------------------------------
__global__ __launch_bounds__(256) void k3a_scan(unsigned int* BuP, float* __restrict__ innerRe,
                                                const float2* __restrict__ cin,
                                                const float* __restrict__ lamre,
                                                const float* __restrict__ lamim) {
  int b = blockIdx.x >> 7, c = blockIdx.x & 127, n = threadIdx.x;
  size_t row0 = (size_t)b * 4096 + c * 32;
  float2 s0 = cin[((size_t)b * 128 + c) * 256 + n];
  float sr = s0.x, si = s0.y;
  float lr = lamre[n], li = lamim[n];
  #pragma unroll 4
  for (int j = 0; j < 32; ++j) {
    size_t idx = (row0 + j) * 256 + n;
    unsigned int v = BuP[idx];                          // read Bu FIRST
    BuP[idx] = (unsigned int)f2bf(sr) | ((unsigned int)f2bf(si) << 16);
    innerRe[idx] = sr;                                  // inner real (pre-state)
    float br = bf2f(v & 0xffffu), bi = bf2f(v >> 16);
    float nr = lr * sr - li * si + br;
    float ni = lr * si + li * sr + bi;
    sr = nr; si = ni;
  }
}

// ---------------------------------------------------------------------------
// K3b v4: B-register-stationary output GEMM. M=32/block, grid 2048, 256 thr
// (4 waves); wave w owns cols w*64..w*64+63 (4 col-tiles). breg[2][4][2] dbuf
// over 12 phases x 2 kk. Per kk: 2 af LDS reads feed 8 MFMAs. 3 blocks/CU.
// Staging reads own SPack rows before barrier; epilogue overwrites after.
// ---------------------------------------------------------------------------
__global__ __launch_bounds__(256, 4) void k3b_breg(const float* __restrict__ in,
                                                   const unsigned short* SPack,
                                                   const unsigned short* __restrict__ W2t,
                                                   float* outp) {
  __shared__ unsigned short lA[32 * 776];   // 49664 B
  int tid = threadIdx.x, lane = tid & 63, w = tid >> 6;   // w in [0,4)
  int l15 = lane & 15, q = lane >> 4;
  size_t row0 = (size_t)blockIdx.x * 32;

  s16x8 breg[2][4][2];                      // [buf][ct][t]
  auto loadB = [&](int buf, int ph) {
    #pragma unroll
    for (int ct = 0; ct < 4; ++ct)
      #pragma unroll
      for (int t = 0; t < 2; ++t) {
        int kk = ph * 2 + t;
        int c = w * 64 + ct * 16 + l15;
        breg[buf][ct][t] = *reinterpret_cast<const s16x8*>(
            W2t + ((size_t)kk * 256 + c) * 32 + q * 8);
      }
  };

  loadB(0, 0);                              // issue early, overlaps staging

  // stage lA cols 0..511: packed bf16 states (32 rows x 512 shorts, 2048 uint4)
  #pragma unroll
  for (int i = 0; i < 8; ++i) {
    int chunk = i * 256 + tid;
    int r = chunk >> 6, c8 = (chunk & 63) * 8;
    *reinterpret_cast<uint4*>(&lA[r * 776 + c8]) =
        *reinterpret_cast<const uint4*>(SPack + (row0 + r) * 512 + c8);
  }
  // stage lA cols 512..767: u f32 -> bf16 (2048 float4)
  #pragma unroll
  for (int i = 0; i < 8; ++i) {
    int chunk = i * 256 + tid;
    int m = chunk >> 6, h0 = (chunk & 63) * 4;
    float4 v = *reinterpret_cast<const float4*>(in + (row0 + m) * 256 + h0);
    ushort4 s; s.x = f2bf(v.x); s.y = f2bf(v.y); s.z = f2bf(v.z); s.w = f2bf(v.w);
    *reinterpret_cast<ushort4*>(&lA[m * 776 + 512 + h0]) = s;
  }
  __syncthreads();

  f32x4 acc[2][4];
  #pragma unroll
  for (int mt = 0; mt < 2; ++mt)
    #pragma unroll
    for (int ct = 0; ct < 4; ++ct) acc[mt][ct] = f32x4{0.f, 0.f, 0.f, 0.f};

  #pragma unroll
  for (int ph = 0; ph < 12; ++ph) {
    const int cur = ph & 1;
    if (ph < 11) loadB(cur ^ 1, ph + 1);    // prefetch next phase into other buf
    #pragma unroll
    for (int t = 0; t < 2; ++t) {
      int kk = ph * 2 + t;
      #pragma unroll
      for (int mt = 0; mt < 2; ++mt) {
        s16x8 af = *reinterpret_cast<const s16x8*>(
            &lA[(mt * 16 + l15) * 776 + kk * 32 + q * 8]);
        #pragma unroll
        for (int ct = 0; ct < 4; ++ct)
          acc[mt][ct] = mfma16(af, breg[cur][ct][t], acc[mt][ct]);
      }
    }
  }

  // epilogue: overwrite this block's own SPack rows with the final output
  #pragma unroll
  for (int mt = 0; mt < 2; ++mt)
    #pragma unroll
    for (int ct = 0; ct < 4; ++ct)
      #pragma unroll
      for (int r = 0; r < 4; ++r) {
        size_t row = row0 + mt * 16 + q * 4 + r;
        int col = w * 64 + ct * 16 + l15;
        outp[row * 256 + col] = acc[mt][ct][r];
      }
}

// ---------------------------------------------------------------------------
extern "C" void kernel_launch(void* const* d_in, const int* in_sizes, int n_in,
                              void* d_out, int out_size, void* d_ws, size_t ws_size,
                              hipStream_t stream) {
  (void)in_sizes; (void)n_in; (void)out_size;
  const float* in       = (const float*)d_in[0];
  const float* nu_log   = (const float*)d_in[1];
  const float* theta_log= (const float*)d_in[2];
  const float* gamma_log= (const float*)d_in[3];
  const float* B_re     = (const float*)d_in[4];
  const float* B_im     = (const float*)d_in[5];
  const float* C_re     = (const float*)d_in[6];
  const float* C_im     = (const float*)d_in[7];
  const float* Dm       = (const float*)d_in[8];

  // ws: W1 [0,256K) | W2f [256K,1M) | lam @1M | W2t @1.25M | cl @2M (4M) | cin @6M (4M)
  if (ws_size < (size_t)10 * 1024 * 1024) return;
  char* ws = (char*)d_ws;
  unsigned short* W1 = (unsigned short*)(ws + 0);
  float* W2f   = (float*)(ws + 262144);
  float* lamre  = (float*)(ws + 1048576);
  float* lamim  = lamre + 256;
  float* lamLre = lamre + 512;
  float* lamLim = lamre + 768;
  unsigned short* W2t = (unsigned short*)(ws + 1310720);
  float2* cl  = (float2*)(ws + (size_t)2 * 1024 * 1024);
  float2* cin = (float2*)(ws + (size_t)6 * 1024 * 1024);

  unsigned int* BuP = (unsigned int*)d_out;                  // [0,64MB): Bu -> states -> output
  float* innerRe = (float*)d_out + (size_t)16777216;         // [64,128MB): inner real

  k0_mix<<<1281, 256, 0, stream>>>(nu_log, theta_log, gamma_log, B_re, B_im, C_re, C_im, Dm,
                                   W1, W2f, lamre, lamim, lamLre, lamLim);
  k0b_tile<<<768, 256, 0, stream>>>(W2f, W2t);
  k1_bstat<<<1024, 1024, 0, stream>>>(in, W1, BuP, lamre, lamim, cl);
  k2b_scan<<<16, 256, 0, stream>>>(cl, cin, lamLre, lamLim);
  k3a_scan<<<2048, 256, 0, stream>>>(BuP, innerRe, cin, lamre, lamim);
  k3b_breg<<<2048, 256, 0, stream>>>(in, (const unsigned short*)BuP, W2t, (float*)BuP);
}

// Round 19
// 146.318 us; speedup vs baseline: 1.0375x; 1.0375x over previous
//
#include <hip/hip_runtime.h>

// LRU r19: k3b REVERTED to r17-green v3 (r18's v4 regressed: more blocks =
// more W2t re-loads, 2-kk phases too shallow to hide L2 latency).
// ONLY new change: k3a v2 — batch-prefetch the 32 Bu loads into registers
// (loads leave the serial scan chain; pure-FMA chain + streamed stores).
// k3a/k3b split PERMANENT (r3/r4, r9/r10, r14/r15 all failed intra-kernel
// state->MFMA feeds; split is green).
// d_out = [0,64MB) output f32 | [64,128MB) inner-real f32.
// Region lifecycle:
//   [0,64MB):  k1 writes packed Bu (bf16 re|im u32) -> k3a reads then
//              overwrites per-thread with packed bf16 states -> k3b stages its
//              64 rows (before barrier) then epilogue overwrites with output.
//   [64,128MB): untouched until k3a writes inner-real f32 (exact, final).

typedef float  f32x4 __attribute__((ext_vector_type(4)));
typedef short  s16x8 __attribute__((ext_vector_type(8)));

__device__ __forceinline__ unsigned short f2bf(float x) {
  unsigned int u = __builtin_bit_cast(unsigned int, x);
  u += 0x7FFFu + ((u >> 16) & 1u);            // round-to-nearest-even
  return (unsigned short)(u >> 16);
}
__device__ __forceinline__ float bf2f(unsigned int s) {
  unsigned int u = s << 16;
  return __builtin_bit_cast(float, u);
}
__device__ __forceinline__ f32x4 mfma16(s16x8 a, s16x8 b, f32x4 c) {
  return __builtin_amdgcn_mfma_f32_16x16x32_bf16(a, b, c, 0, 0, 0);
}

// ---------------------------------------------------------------------------
// K0: W1 bf16 tiled + W2f f32 [k*256+o] + lam arrays (green, unchanged).
// ---------------------------------------------------------------------------
__global__ void k0_mix(const float* __restrict__ nu_log, const float* __restrict__ theta_log,
                       const float* __restrict__ gamma_log,
                       const float* __restrict__ B_re, const float* __restrict__ B_im,
                       const float* __restrict__ C_re, const float* __restrict__ C_im,
                       const float* __restrict__ Dm,
                       unsigned short* __restrict__ W1, float* __restrict__ W2f,
                       float* __restrict__ lamre, float* __restrict__ lamim,
                       float* __restrict__ lamLre, float* __restrict__ lamLim) {
  int idx = blockIdx.x * 256 + threadIdx.x;
  if (idx < 131072) {
    int ki = idx & 31; int np_ = (idx >> 5) & 511; int kk = idx >> 14;
    int k = kk * 32 + ki; int n = np_ & 255;
    float g = expf(gamma_log[n]);
    float v = (np_ < 256) ? B_re[n * 256 + k] : B_im[n * 256 + k];
    W1[idx] = f2bf(g * v);
  } else if (idx < 327680) {
    int j = idx - 131072;
    int k = j >> 8, o = j & 255;
    float v;
    if (k < 512) { int n = k >> 1; v = (k & 1) ? -C_im[o * 256 + n] : C_re[o * 256 + n]; }
    else         { v = Dm[o * 256 + (k - 512)]; }
    W2f[j] = v;
  } else if (idx < 327936) {
    int n = idx - 327680;
    float la = expf(-expf(nu_log[n]));
    float th = expf(theta_log[n]);
    float lr = la * cosf(th), li = la * sinf(th);
    lamre[n] = lr; lamim[n] = li;
    float r = lr, i = li;
    #pragma unroll
    for (int t = 0; t < 5; ++t) { float nr = r * r - i * i; float ni = 2.f * r * i; r = nr; i = ni; }
    lamLre[n] = r; lamLim[n] = i;
  }
}

// ---------------------------------------------------------------------------
// K0b: tile W2f into bf16 W2t[(kk*256+o)*32+ki] (green, unchanged).
// ---------------------------------------------------------------------------
__global__ void k0b_tile(const float* __restrict__ W2f, unsigned short* __restrict__ W2t) {
  int j = blockIdx.x * 256 + threadIdx.x;          // [0,196608)
  int ki = j & 31, o = (j >> 5) & 255, kk = j >> 13;
  W2t[j] = f2bf(W2f[(kk * 32 + ki) * 256 + o]);
}

// ---------------------------------------------------------------------------
// K1 v2 (green r17, unchanged): B-register-stationary Bu-GEMM + packed stores
// + in-register chunk reduction.
// ---------------------------------------------------------------------------
__global__ __launch_bounds__(1024, 4) void k1_bstat(const float* __restrict__ in,
                                                    const unsigned short* __restrict__ W1,
                                                    unsigned int* __restrict__ BuP,
                                                    const float* __restrict__ lamre,
                                                    const float* __restrict__ lamim,
                                                    float2* __restrict__ cl) {
  __shared__ unsigned short lA[64 * 264];   // 33792 B
  int tid = threadIdx.x, lane = tid & 63, w = tid >> 6;   // w in [0,16)
  int l15 = lane & 15, q = lane >> 4;
  int n = w * 16 + l15;
  size_t row0 = (size_t)blockIdx.x * 64;

  s16x8 breg[2][2][2];                      // [buf][plane][t]
  auto loadB = [&](int buf, int ph) {
    #pragma unroll
    for (int p = 0; p < 2; ++p)
      #pragma unroll
      for (int t = 0; t < 2; ++t) {
        int kk = ph * 2 + t;
        breg[buf][p][t] = *reinterpret_cast<const s16x8*>(
            W1 + (size_t)(kk * 512 + p * 256 + n) * 32 + q * 8);
      }
  };

  loadB(0, 0);                              // issue early, overlaps staging

  #pragma unroll
  for (int i = 0; i < 4; ++i) {
    int chunk = i * 1024 + tid;             // 4096 float4 chunks
    int m = chunk >> 6, h0 = (chunk & 63) * 4;
    float4 v = *reinterpret_cast<const float4*>(in + (row0 + m) * 256 + h0);
    ushort4 s; s.x = f2bf(v.x); s.y = f2bf(v.y); s.z = f2bf(v.z); s.w = f2bf(v.w);
    *reinterpret_cast<ushort4*>(&lA[m * 264 + h0]) = s;
  }
  __syncthreads();

  f32x4 acc[4][2];
  #pragma unroll
  for (int mt = 0; mt < 4; ++mt)
    #pragma unroll
    for (int p = 0; p < 2; ++p) acc[mt][p] = f32x4{0.f, 0.f, 0.f, 0.f};

  #pragma unroll
  for (int ph = 0; ph < 4; ++ph) {
    const int cur = ph & 1;
    if (ph < 3) loadB(cur ^ 1, ph + 1);     // prefetch next phase into other buf
    #pragma unroll
    for (int t = 0; t < 2; ++t) {
      int kk = ph * 2 + t;
      #pragma unroll
      for (int mt = 0; mt < 4; ++mt) {
        s16x8 af = *reinterpret_cast<const s16x8*>(
            &lA[(mt * 16 + l15) * 264 + kk * 32 + q * 8]);
        acc[mt][0] = mfma16(af, breg[cur][0][t], acc[mt][0]);
        acc[mt][1] = mfma16(af, breg[cur][1][t], acc[mt][1]);
      }
    }
  }

  // epilogue: pack (re,im) bf16 pairs
  #pragma unroll
  for (int mt = 0; mt < 4; ++mt)
    #pragma unroll
    for (int r = 0; r < 4; ++r) {
      size_t row = row0 + mt * 16 + q * 4 + r;
      unsigned int pk = (unsigned int)f2bf(acc[mt][0][r]) |
                        ((unsigned int)f2bf(acc[mt][1][r]) << 16);
      BuP[row * 256 + n] = pk;
    }

  // in-register chunk reduction (r17-green algebra)
  {
    float lr = lamre[n], li = lamim[n];
    float l2r = lr * lr - li * li, l2i = 2.f * lr * li;
    float l4r = l2r * l2r - l2i * l2i, l4i = 2.f * l2r * l2i;
    float p8r = l4r * l4r - l4i * l4i, p8i = 2.f * l4r * l4i;
    float p12r = p8r * l4r - p8i * l4i, p12i = p8r * l4i + p8i * l4r;
    float p16r = p8r * p8r - p8i * p8i, p16i = 2.f * p8r * p8i;
    float e1r, e1i;                         // lam^{12-4q}
    if (q == 0)      { e1r = p12r; e1i = p12i; }
    else if (q == 1) { e1r = p8r;  e1i = p8i;  }
    else if (q == 2) { e1r = l4r;  e1i = l4i;  }
    else             { e1r = 1.f;  e1i = 0.f;  }
    float e0r = e1r * p16r - e1i * p16i;    // lam^{28-4q}
    float e0i = e1r * p16i + e1i * p16r;
    #pragma unroll
    for (int ch = 0; ch < 2; ++ch) {
      float hr[2], hi[2];
      #pragma unroll
      for (int h = 0; h < 2; ++h) {
        int mt = ch * 2 + h;
        float xr = 0.f, xi = 0.f;
        #pragma unroll
        for (int r = 0; r < 4; ++r) {
          float br = acc[mt][0][r], bi2 = acc[mt][1][r];
          float nr2 = lr * xr - li * xi + br;
          float ni2 = lr * xi + li * xr + bi2;
          xr = nr2; xi = ni2;
        }
        hr[h] = xr; hi[h] = xi;
      }
      float Tr = e0r * hr[0] - e0i * hi[0] + e1r * hr[1] - e1i * hi[1];
      float Ti = e0r * hi[0] + e0i * hr[0] + e1r * hi[1] + e1i * hr[1];
      Tr += __shfl_xor(Tr, 16); Ti += __shfl_xor(Ti, 16);
      Tr += __shfl_xor(Tr, 32); Ti += __shfl_xor(Ti, 32);
      if (q == 0) {
        size_t C = (size_t)blockIdx.x * 2 + ch;
        cl[C * 256 + n] = make_float2(Tr, Ti);
      }
    }
  }
}

// ---------------------------------------------------------------------------
// K2b: carry scan (green, unchanged).
// ---------------------------------------------------------------------------
__global__ void k2b_scan(const float2* __restrict__ cl, float2* __restrict__ cin,
                         const float* __restrict__ lamLre, const float* __restrict__ lamLim) {
  int b = blockIdx.x, n = threadIdx.x;
  float lr = lamLre[n], li = lamLim[n];
  float sr = 0.f, si = 0.f;
  #pragma unroll 4
  for (int c = 0; c < 128; ++c) {
    size_t idx = ((size_t)b * 128 + c) * 256 + n;
    float2 L = cl[idx];
    cin[idx] = make_float2(sr, si);
    float nr = lr * sr - li * si + L.x;
    float ni = lr * si + li * sr + L.y;
    sr = nr; si = ni;
  }
}

// ---------------------------------------------------------------------------
// K3a v2: f32 scan with batch-prefetched Bu. Same indices/ownership as green
// k3a; the 32 loads are hoisted into a register batch ahead of the pure-FMA
// scan chain (loads overlap, chain no longer eats load-use latency).
// ---------------------------------------------------------------------------
__global__ __launch_bounds__(256) void k3a_scan(unsigned int* BuP, float* __restrict__ innerRe,
                                                const float2* __restrict__ cin,
                                                const float* __restrict__ lamre,
                                                const float* __restrict__ lamim) {
  int b = blockIdx.x >> 7, c = blockIdx.x & 127, n = threadIdx.x;
  size_t row0 = (size_t)b * 4096 + c * 32;
  unsigned int bu[32];
  #pragma unroll
  for (int j = 0; j < 32; ++j) bu[j] = BuP[(row0 + j) * 256 + n];   // all in flight
  float2 s0 = cin[((size_t)b * 128 + c) * 256 + n];
  float sr = s0.x, si = s0.y;
  float lr = lamre[n], li = lamim[n];
  #pragma unroll
  for (int j = 0; j < 32; ++j) {
    size_t idx = (row0 + j) * 256 + n;
    BuP[idx] = (unsigned int)f2bf(sr) | ((unsigned int)f2bf(si) << 16);
    innerRe[idx] = sr;                                  // inner real (pre-state)
    float br = bf2f(bu[j] & 0xffffu), bi = bf2f(bu[j] >> 16);
    float nr = lr * sr - li * si + br;
    float ni = lr * si + li * sr + bi;
    sr = nr; si = ni;
  }
}

// ---------------------------------------------------------------------------
// K3b v3 (green r16/r17, unchanged): B-register-stationary output GEMM,
// M=64/block, 1024 threads (16 waves), wave w owns cols w*16..w*16+15.
// ---------------------------------------------------------------------------
__global__ __launch_bounds__(1024, 4) void k3b_breg(const float* __restrict__ in,
                                                    const unsigned short* SPack,
                                                    const unsigned short* __restrict__ W2t,
                                                    float* outp) {
  __shared__ unsigned short lA[64 * 776];   // 99328 B
  int tid = threadIdx.x, lane = tid & 63, w = tid >> 6;   // w in [0,16)
  int l15 = lane & 15, q = lane >> 4;
  size_t row0 = (size_t)blockIdx.x * 64;

  s16x8 breg[2][4];                         // [buf][t]
  auto loadB = [&](int buf, int p) {
    #pragma unroll
    for (int t = 0; t < 4; ++t) {
      int kk = p * 4 + t;
      int c = w * 16 + l15;
      breg[buf][t] = *reinterpret_cast<const s16x8*>(
          W2t + ((size_t)kk * 256 + c) * 32 + q * 8);
    }
  };

  loadB(0, 0);                              // issue early, overlaps staging

  // stage lA cols 0..511: packed bf16 states (64 rows x 512 shorts)
  #pragma unroll
  for (int i = 0; i < 4; ++i) {
    int chunk = i * 1024 + tid;             // 4096 chunks of 8 shorts
    int r = chunk >> 6, c8 = (chunk & 63) * 8;
    *reinterpret_cast<uint4*>(&lA[r * 776 + c8]) =
        *reinterpret_cast<const uint4*>(SPack + (row0 + r) * 512 + c8);
  }
  // stage lA cols 512..767: u f32 -> bf16 (64 rows x 64 float4)
  #pragma unroll
  for (int i = 0; i < 4; ++i) {
    int chunk = i * 1024 + tid;             // 4096 float4 chunks
    int m = chunk >> 6, h0 = (chunk & 63) * 4;
    float4 v = *reinterpret_cast<const float4*>(in + (row0 + m) * 256 + h0);
    ushort4 s; s.x = f2bf(v.x); s.y = f2bf(v.y); s.z = f2bf(v.z); s.w = f2bf(v.w);
    *reinterpret_cast<ushort4*>(&lA[m * 776 + 512 + h0]) = s;
  }
  __syncthreads();

  f32x4 acc[4];
  #pragma unroll
  for (int mt = 0; mt < 4; ++mt) acc[mt] = f32x4{0.f, 0.f, 0.f, 0.f};

  #pragma unroll
  for (int p = 0; p < 6; ++p) {
    const int cur = p & 1;
    if (p < 5) loadB(cur ^ 1, p + 1);       // prefetch next phase into other buf
    #pragma unroll
    for (int t = 0; t < 4; ++t) {
      int kk = p * 4 + t;
      #pragma unroll
      for (int mt = 0; mt < 4; ++mt) {
        s16x8 af = *reinterpret_cast<const s16x8*>(
            &lA[(mt * 16 + l15) * 776 + kk * 32 + q * 8]);
        acc[mt] = mfma16(af, breg[cur][t], acc[mt]);
      }
    }
  }

  // epilogue: overwrite this block's own SPack rows with the final output
  #pragma unroll
  for (int mt = 0; mt < 4; ++mt)
    #pragma unroll
    for (int r = 0; r < 4; ++r) {
      size_t row = row0 + mt * 16 + q * 4 + r;
      int col = w * 16 + l15;
      outp[row * 256 + col] = acc[mt][r];
    }
}

// ---------------------------------------------------------------------------
extern "C" void kernel_launch(void* const* d_in, const int* in_sizes, int n_in,
                              void* d_out, int out_size, void* d_ws, size_t ws_size,
                              hipStream_t stream) {
  (void)in_sizes; (void)n_in; (void)out_size;
  const float* in       = (const float*)d_in[0];
  const float* nu_log   = (const float*)d_in[1];
  const float* theta_log= (const float*)d_in[2];
  const float* gamma_log= (const float*)d_in[3];
  const float* B_re     = (const float*)d_in[4];
  const float* B_im     = (const float*)d_in[5];
  const float* C_re     = (const float*)d_in[6];
  const float* C_im     = (const float*)d_in[7];
  const float* Dm       = (const float*)d_in[8];

  // ws: W1 [0,256K) | W2f [256K,1M) | lam @1M | W2t @1.25M | cl @2M (4M) | cin @6M (4M)
  if (ws_size < (size_t)10 * 1024 * 1024) return;
  char* ws = (char*)d_ws;
  unsigned short* W1 = (unsigned short*)(ws + 0);
  float* W2f   = (float*)(ws + 262144);
  float* lamre  = (float*)(ws + 1048576);
  float* lamim  = lamre + 256;
  float* lamLre = lamre + 512;
  float* lamLim = lamre + 768;
  unsigned short* W2t = (unsigned short*)(ws + 1310720);
  float2* cl  = (float2*)(ws + (size_t)2 * 1024 * 1024);
  float2* cin = (float2*)(ws + (size_t)6 * 1024 * 1024);

  unsigned int* BuP = (unsigned int*)d_out;                  // [0,64MB): Bu -> states -> output
  float* innerRe = (float*)d_out + (size_t)16777216;         // [64,128MB): inner real

  k0_mix<<<1281, 256, 0, stream>>>(nu_log, theta_log, gamma_log, B_re, B_im, C_re, C_im, Dm,
                                   W1, W2f, lamre, lamim, lamLre, lamLim);
  k0b_tile<<<768, 256, 0, stream>>>(W2f, W2t);
  k1_bstat<<<1024, 1024, 0, stream>>>(in, W1, BuP, lamre, lamim, cl);
  k2b_scan<<<16, 256, 0, stream>>>(cl, cin, lamLre, lamLim);
  k3a_scan<<<2048, 256, 0, stream>>>(BuP, innerRe, cin, lamre, lamim);
  k3b_breg<<<1024, 1024, 0, stream>>>(in, (const unsigned short*)BuP, W2t, (float*)BuP);
}

// Round 20
// 139.175 us; speedup vs baseline: 1.0907x; 1.0513x over previous
//
#include <hip/hip_runtime.h>

// LRU r20: (1) k0b/W2f eliminated — k0 computes the bf16-tiled W2t directly
// from C_re/C_im/D (one fewer launch); (2) k2b v2 — cl batch-prefetched in
// 8x16 register batches (kills the 225cyc/iter load-use serialization).
// k1/k3a/k3b byte-identical to r19-green.
// k3a/k3b split PERMANENT (r3/r4, r9/r10, r14/r15 all failed intra-kernel
// state->MFMA feeds; split is green).
// d_out = [0,64MB) output f32 | [64,128MB) inner-real f32.
// Region lifecycle:
//   [0,64MB):  k1 writes packed Bu (bf16 re|im u32) -> k3a reads then
//              overwrites per-thread with packed bf16 states -> k3b stages its
//              64 rows (before barrier) then epilogue overwrites with output.
//   [64,128MB): untouched until k3a writes inner-real f32 (exact, final).

typedef float  f32x4 __attribute__((ext_vector_type(4)));
typedef short  s16x8 __attribute__((ext_vector_type(8)));

__device__ __forceinline__ unsigned short f2bf(float x) {
  unsigned int u = __builtin_bit_cast(unsigned int, x);
  u += 0x7FFFu + ((u >> 16) & 1u);            // round-to-nearest-even
  return (unsigned short)(u >> 16);
}
__device__ __forceinline__ float bf2f(unsigned int s) {
  unsigned int u = s << 16;
  return __builtin_bit_cast(float, u);
}
__device__ __forceinline__ f32x4 mfma16(s16x8 a, s16x8 b, f32x4 c) {
  return __builtin_amdgcn_mfma_f32_16x16x32_bf16(a, b, c, 0, 0, 0);
}

// ---------------------------------------------------------------------------
// K0 v2: W1 bf16 tiled + W2t bf16 tiled DIRECTLY (no W2f intermediate) + lam.
// W2t[j], j=(kk*256+o)*32+ki, k=kk*32+ki:
//   k<512: even k -> C_re[o][k/2], odd -> -C_im[o][k/2]; k>=512 -> D[o][k-512].
// (Same value function as the green k0_mix/k0b_tile composition.)
// ---------------------------------------------------------------------------
__global__ void k0_mix(const float* __restrict__ nu_log, const float* __restrict__ theta_log,
                       const float* __restrict__ gamma_log,
                       const float* __restrict__ B_re, const float* __restrict__ B_im,
                       const float* __restrict__ C_re, const float* __restrict__ C_im,
                       const float* __restrict__ Dm,
                       unsigned short* __restrict__ W1, unsigned short* __restrict__ W2t,
                       float* __restrict__ lamre, float* __restrict__ lamim,
                       float* __restrict__ lamLre, float* __restrict__ lamLim) {
  int idx = blockIdx.x * 256 + threadIdx.x;
  if (idx < 131072) {
    int ki = idx & 31; int np_ = (idx >> 5) & 511; int kk = idx >> 14;
    int k = kk * 32 + ki; int n = np_ & 255;
    float g = expf(gamma_log[n]);
    float v = (np_ < 256) ? B_re[n * 256 + k] : B_im[n * 256 + k];
    W1[idx] = f2bf(g * v);
  } else if (idx < 327680) {
    int j = idx - 131072;
    int ki = j & 31, o = (j >> 5) & 255, kk = j >> 13;
    int k = kk * 32 + ki;
    float v;
    if (k < 512) { int n = k >> 1; v = (k & 1) ? -C_im[o * 256 + n] : C_re[o * 256 + n]; }
    else         { v = Dm[o * 256 + (k - 512)]; }
    W2t[j] = f2bf(v);
  } else if (idx < 327936) {
    int n = idx - 327680;
    float la = expf(-expf(nu_log[n]));
    float th = expf(theta_log[n]);
    float lr = la * cosf(th), li = la * sinf(th);
    lamre[n] = lr; lamim[n] = li;
    float r = lr, i = li;
    #pragma unroll
    for (int t = 0; t < 5; ++t) { float nr = r * r - i * i; float ni = 2.f * r * i; r = nr; i = ni; }
    lamLre[n] = r; lamLim[n] = i;
  }
}

// ---------------------------------------------------------------------------
// K1 v2 (green r17, unchanged): B-register-stationary Bu-GEMM + packed stores
// + in-register chunk reduction.
// ---------------------------------------------------------------------------
__global__ __launch_bounds__(1024, 4) void k1_bstat(const float* __restrict__ in,
                                                    const unsigned short* __restrict__ W1,
                                                    unsigned int* __restrict__ BuP,
                                                    const float* __restrict__ lamre,
                                                    const float* __restrict__ lamim,
                                                    float2* __restrict__ cl) {
  __shared__ unsigned short lA[64 * 264];   // 33792 B
  int tid = threadIdx.x, lane = tid & 63, w = tid >> 6;   // w in [0,16)
  int l15 = lane & 15, q = lane >> 4;
  int n = w * 16 + l15;
  size_t row0 = (size_t)blockIdx.x * 64;

  s16x8 breg[2][2][2];                      // [buf][plane][t]
  auto loadB = [&](int buf, int ph) {
    #pragma unroll
    for (int p = 0; p < 2; ++p)
      #pragma unroll
      for (int t = 0; t < 2; ++t) {
        int kk = ph * 2 + t;
        breg[buf][p][t] = *reinterpret_cast<const s16x8*>(
            W1 + (size_t)(kk * 512 + p * 256 + n) * 32 + q * 8);
      }
  };

  loadB(0, 0);                              // issue early, overlaps staging

  #pragma unroll
  for (int i = 0; i < 4; ++i) {
    int chunk = i * 1024 + tid;             // 4096 float4 chunks
    int m = chunk >> 6, h0 = (chunk & 63) * 4;
    float4 v = *reinterpret_cast<const float4*>(in + (row0 + m) * 256 + h0);
    ushort4 s; s.x = f2bf(v.x); s.y = f2bf(v.y); s.z = f2bf(v.z); s.w = f2bf(v.w);
    *reinterpret_cast<ushort4*>(&lA[m * 264 + h0]) = s;
  }
  __syncthreads();

  f32x4 acc[4][2];
  #pragma unroll
  for (int mt = 0; mt < 4; ++mt)
    #pragma unroll
    for (int p = 0; p < 2; ++p) acc[mt][p] = f32x4{0.f, 0.f, 0.f, 0.f};

  #pragma unroll
  for (int ph = 0; ph < 4; ++ph) {
    const int cur = ph & 1;
    if (ph < 3) loadB(cur ^ 1, ph + 1);     // prefetch next phase into other buf
    #pragma unroll
    for (int t = 0; t < 2; ++t) {
      int kk = ph * 2 + t;
      #pragma unroll
      for (int mt = 0; mt < 4; ++mt) {
        s16x8 af = *reinterpret_cast<const s16x8*>(
            &lA[(mt * 16 + l15) * 264 + kk * 32 + q * 8]);
        acc[mt][0] = mfma16(af, breg[cur][0][t], acc[mt][0]);
        acc[mt][1] = mfma16(af, breg[cur][1][t], acc[mt][1]);
      }
    }
  }

  // epilogue: pack (re,im) bf16 pairs
  #pragma unroll
  for (int mt = 0; mt < 4; ++mt)
    #pragma unroll
    for (int r = 0; r < 4; ++r) {
      size_t row = row0 + mt * 16 + q * 4 + r;
      unsigned int pk = (unsigned int)f2bf(acc[mt][0][r]) |
                        ((unsigned int)f2bf(acc[mt][1][r]) << 16);
      BuP[row * 256 + n] = pk;
    }

  // in-register chunk reduction (r17-green algebra)
  {
    float lr = lamre[n], li = lamim[n];
    float l2r = lr * lr - li * li, l2i = 2.f * lr * li;
    float l4r = l2r * l2r - l2i * l2i, l4i = 2.f * l2r * l2i;
    float p8r = l4r * l4r - l4i * l4i, p8i = 2.f * l4r * l4i;
    float p12r = p8r * l4r - p8i * l4i, p12i = p8r * l4i + p8i * l4r;
    float p16r = p8r * p8r - p8i * p8i, p16i = 2.f * p8r * p8i;
    float e1r, e1i;                         // lam^{12-4q}
    if (q == 0)      { e1r = p12r; e1i = p12i; }
    else if (q == 1) { e1r = p8r;  e1i = p8i;  }
    else if (q == 2) { e1r = l4r;  e1i = l4i;  }
    else             { e1r = 1.f;  e1i = 0.f;  }
    float e0r = e1r * p16r - e1i * p16i;    // lam^{28-4q}
    float e0i = e1r * p16i + e1i * p16r;
    #pragma unroll
    for (int ch = 0; ch < 2; ++ch) {
      float hr[2], hi[2];
      #pragma unroll
      for (int h = 0; h < 2; ++h) {
        int mt = ch * 2 + h;
        float xr = 0.f, xi = 0.f;
        #pragma unroll
        for (int r = 0; r < 4; ++r) {
          float br = acc[mt][0][r], bi2 = acc[mt][1][r];
          float nr2 = lr * xr - li * xi + br;
          float ni2 = lr * xi + li * xr + bi2;
          xr = nr2; xi = ni2;
        }
        hr[h] = xr; hi[h] = xi;
      }
      float Tr = e0r * hr[0] - e0i * hi[0] + e1r * hr[1] - e1i * hi[1];
      float Ti = e0r * hi[0] + e0i * hr[0] + e1r * hi[1] + e1i * hr[1];
      Tr += __shfl_xor(Tr, 16); Ti += __shfl_xor(Ti, 16);
      Tr += __shfl_xor(Tr, 32); Ti += __shfl_xor(Ti, 32);
      if (q == 0) {
        size_t C = (size_t)blockIdx.x * 2 + ch;
        cl[C * 256 + n] = make_float2(Tr, Ti);
      }
    }
  }
}

// ---------------------------------------------------------------------------
// K2b v2: carry scan with 8x16 register batch-prefetch of cl (independent
// loads issue together; dependent FMA chain no longer eats L2 latency).
// Same math/order as green k2b.
// ---------------------------------------------------------------------------
__global__ void k2b_scan(const float2* __restrict__ cl, float2* __restrict__ cin,
                         const float* __restrict__ lamLre, const float* __restrict__ lamLim) {
  int b = blockIdx.x, n = threadIdx.x;
  float lr = lamLre[n], li = lamLim[n];
  float sr = 0.f, si = 0.f;
  for (int cb = 0; cb < 8; ++cb) {
    float2 L[16];
    #pragma unroll
    for (int t = 0; t < 16; ++t)
      L[t] = cl[((size_t)b * 128 + cb * 16 + t) * 256 + n];
    #pragma unroll
    for (int t = 0; t < 16; ++t) {
      size_t idx = ((size_t)b * 128 + cb * 16 + t) * 256 + n;
      cin[idx] = make_float2(sr, si);
      float nr = lr * sr - li * si + L[t].x;
      float ni = lr * si + li * sr + L[t].y;
      sr = nr; si = ni;
    }
  }
}

// ---------------------------------------------------------------------------
// K3a v2 (green r19, unchanged): f32 scan with batch-prefetched Bu.
// ---------------------------------------------------------------------------
__global__ __launch_bounds__(256) void k3a_scan(unsigned int* BuP, float* __restrict__ innerRe,
                                                const float2* __restrict__ cin,
                                                const float* __restrict__ lamre,
                                                const float* __restrict__ lamim) {
  int b = blockIdx.x >> 7, c = blockIdx.x & 127, n = threadIdx.x;
  size_t row0 = (size_t)b * 4096 + c * 32;
  unsigned int bu[32];
  #pragma unroll
  for (int j = 0; j < 32; ++j) bu[j] = BuP[(row0 + j) * 256 + n];   // all in flight
  float2 s0 = cin[((size_t)b * 128 + c) * 256 + n];
  float sr = s0.x, si = s0.y;
  float lr = lamre[n], li = lamim[n];
  #pragma unroll
  for (int j = 0; j < 32; ++j) {
    size_t idx = (row0 + j) * 256 + n;
    BuP[idx] = (unsigned int)f2bf(sr) | ((unsigned int)f2bf(si) << 16);
    innerRe[idx] = sr;                                  // inner real (pre-state)
    float br = bf2f(bu[j] & 0xffffu), bi = bf2f(bu[j] >> 16);
    float nr = lr * sr - li * si + br;
    float ni = lr * si + li * sr + bi;
    sr = nr; si = ni;
  }
}

// ---------------------------------------------------------------------------
// K3b v3 (green r16/r17, unchanged): B-register-stationary output GEMM,
// M=64/block, 1024 threads (16 waves), wave w owns cols w*16..w*16+15.
// ---------------------------------------------------------------------------
__global__ __launch_bounds__(1024, 4) void k3b_breg(const float* __restrict__ in,
                                                    const unsigned short* SPack,
                                                    const unsigned short* __restrict__ W2t,
                                                    float* outp) {
  __shared__ unsigned short lA[64 * 776];   // 99328 B
  int tid = threadIdx.x, lane = tid & 63, w = tid >> 6;   // w in [0,16)
  int l15 = lane & 15, q = lane >> 4;
  size_t row0 = (size_t)blockIdx.x * 64;

  s16x8 breg[2][4];                         // [buf][t]
  auto loadB = [&](int buf, int p) {
    #pragma unroll
    for (int t = 0; t < 4; ++t) {
      int kk = p * 4 + t;
      int c = w * 16 + l15;
      breg[buf][t] = *reinterpret_cast<const s16x8*>(
          W2t + ((size_t)kk * 256 + c) * 32 + q * 8);
    }
  };

  loadB(0, 0);                              // issue early, overlaps staging

  // stage lA cols 0..511: packed bf16 states (64 rows x 512 shorts)
  #pragma unroll
  for (int i = 0; i < 4; ++i) {
    int chunk = i * 1024 + tid;             // 4096 chunks of 8 shorts
    int r = chunk >> 6, c8 = (chunk & 63) * 8;
    *reinterpret_cast<uint4*>(&lA[r * 776 + c8]) =
        *reinterpret_cast<const uint4*>(SPack + (row0 + r) * 512 + c8);
  }
  // stage lA cols 512..767: u f32 -> bf16 (64 rows x 64 float4)
  #pragma unroll
  for (int i = 0; i < 4; ++i) {
    int chunk = i * 1024 + tid;             // 4096 float4 chunks
    int m = chunk >> 6, h0 = (chunk & 63) * 4;
    float4 v = *reinterpret_cast<const float4*>(in + (row0 + m) * 256 + h0);
    ushort4 s; s.x = f2bf(v.x); s.y = f2bf(v.y); s.z = f2bf(v.z); s.w = f2bf(v.w);
    *reinterpret_cast<ushort4*>(&lA[m * 776 + 512 + h0]) = s;
  }
  __syncthreads();

  f32x4 acc[4];
  #pragma unroll
  for (int mt = 0; mt < 4; ++mt) acc[mt] = f32x4{0.f, 0.f, 0.f, 0.f};

  #pragma unroll
  for (int p = 0; p < 6; ++p) {
    const int cur = p & 1;
    if (p < 5) loadB(cur ^ 1, p + 1);       // prefetch next phase into other buf
    #pragma unroll
    for (int t = 0; t < 4; ++t) {
      int kk = p * 4 + t;
      #pragma unroll
      for (int mt = 0; mt < 4; ++mt) {
        s16x8 af = *reinterpret_cast<const s16x8*>(
            &lA[(mt * 16 + l15) * 776 + kk * 32 + q * 8]);
        acc[mt] = mfma16(af, breg[cur][t], acc[mt]);
      }
    }
  }

  // epilogue: overwrite this block's own SPack rows with the final output
  #pragma unroll
  for (int mt = 0; mt < 4; ++mt)
    #pragma unroll
    for (int r = 0; r < 4; ++r) {
      size_t row = row0 + mt * 16 + q * 4 + r;
      int col = w * 16 + l15;
      outp[row * 256 + col] = acc[mt][r];
    }
}

// ---------------------------------------------------------------------------
extern "C" void kernel_launch(void* const* d_in, const int* in_sizes, int n_in,
                              void* d_out, int out_size, void* d_ws, size_t ws_size,
                              hipStream_t stream) {
  (void)in_sizes; (void)n_in; (void)out_size;
  const float* in       = (const float*)d_in[0];
  const float* nu_log   = (const float*)d_in[1];
  const float* theta_log= (const float*)d_in[2];
  const float* gamma_log= (const float*)d_in[3];
  const float* B_re     = (const float*)d_in[4];
  const float* B_im     = (const float*)d_in[5];
  const float* C_re     = (const float*)d_in[6];
  const float* C_im     = (const float*)d_in[7];
  const float* Dm       = (const float*)d_in[8];

  // ws: W1 [0,256K) | lam @1M | W2t @1.25M | cl @2M (4M) | cin @6M (4M)
  if (ws_size < (size_t)10 * 1024 * 1024) return;
  char* ws = (char*)d_ws;
  unsigned short* W1 = (unsigned short*)(ws + 0);
  float* lamre  = (float*)(ws + 1048576);
  float* lamim  = lamre + 256;
  float* lamLre = lamre + 512;
  float* lamLim = lamre + 768;
  unsigned short* W2t = (unsigned short*)(ws + 1310720);
  float2* cl  = (float2*)(ws + (size_t)2 * 1024 * 1024);
  float2* cin = (float2*)(ws + (size_t)6 * 1024 * 1024);

  unsigned int* BuP = (unsigned int*)d_out;                  // [0,64MB): Bu -> states -> output
  float* innerRe = (float*)d_out + (size_t)16777216;         // [64,128MB): inner real

  k0_mix<<<1281, 256, 0, stream>>>(nu_log, theta_log, gamma_log, B_re, B_im, C_re, C_im, Dm,
                                   W1, W2t, lamre, lamim, lamLre, lamLim);
  k1_bstat<<<1024, 1024, 0, stream>>>(in, W1, BuP, lamre, lamim, cl);
  k2b_scan<<<16, 256, 0, stream>>>(cl, cin, lamLre, lamLim);
  k3a_scan<<<2048, 256, 0, stream>>>(BuP, innerRe, cin, lamre, lamim);
  k3b_breg<<<1024, 1024, 0, stream>>>(in, (const unsigned short*)BuP, W2t, (float*)BuP);
}